// Round 2
// baseline (301.235 us; speedup 1.0000x reference)
//
#include <hip/hip_runtime.h>
#include <hip/hip_bf16.h>
#include <stdint.h>

#define NSEQ   2048
#define DMODEL 1024
#define NH     16
#define DH     64
#define BATCH  2
#define BH     (BATCH*NH)           // 32
#define MROWS  (BATCH*NSEQ)         // 4096

typedef unsigned short u16;
typedef __attribute__((ext_vector_type(8))) short s16x8;
typedef __attribute__((ext_vector_type(4))) float f32x4;

__device__ __forceinline__ void load16_to_lds(const void* g, void* l) {
    __builtin_amdgcn_global_load_lds(
        (const __attribute__((address_space(1))) void*)g,
        (__attribute__((address_space(3))) void*)l,
        16, 0, 0);
}

__device__ __forceinline__ u16 f2bf(float f) {
    union { float f; uint32_t i; } x; x.f = f;
    uint32_t r = x.i + 0x7FFFu + ((x.i >> 16) & 1u);  // RNE
    return (u16)(r >> 16);
}

// ---------------------------------------------------------------------------
// fp32 -> bf16 conversion. grid (512,1,8): z<4 -> quarter-slices of x (4M),
// z=4..7 -> wq/wk/wv/wo (1M each). 256 thr x 8 elem = 2048 per block.
// ---------------------------------------------------------------------------
__global__ void cvt_kernel(
    const float* __restrict__ x,
    const float* __restrict__ wq, const float* __restrict__ wk,
    const float* __restrict__ wv, const float* __restrict__ wo,
    u16* __restrict__ xb,
    u16* __restrict__ wqb, u16* __restrict__ wkb,
    u16* __restrict__ wvb, u16* __restrict__ wob)
{
    int z = blockIdx.z;
    const float* s = (z < 4) ? x  : (z == 4 ? wq  : z == 5 ? wk  : z == 6 ? wv  : wo);
    u16*         d = (z < 4) ? xb : (z == 4 ? wqb : z == 5 ? wkb : z == 6 ? wvb : wob);
    size_t off = (z < 4) ? ((size_t)z << 20) : 0;
    size_t i = off + (size_t)blockIdx.x * 2048 + (size_t)threadIdx.x * 8;
    float4 a = *(const float4*)(s + i);
    float4 b = *(const float4*)(s + i + 4);
    s16x8 v;
    v[0] = (short)f2bf(a.x); v[1] = (short)f2bf(a.y);
    v[2] = (short)f2bf(a.z); v[3] = (short)f2bf(a.w);
    v[4] = (short)f2bf(b.x); v[5] = (short)f2bf(b.y);
    v[6] = (short)f2bf(b.z); v[7] = (short)f2bf(b.w);
    *(s16x8*)(d + i) = v;
}

// ---------------------------------------------------------------------------
// GEMM: C = A @ W^T.  A:[M][1024] bf16 row-major, W:[1024][1024] bf16 row-major.
// 128x128 tile, BK=64, 256 threads (4 waves, each 64x64 = 4x4 MFMA tiles).
// LDS staged via global_load_lds(16B) with XOR chunk swizzle: chunk c of row r
// stored at position c ^ (r&7)  (8 chunks of 16B per 128B row).
// mode 0: store fp32 C[m][o].  mode 1: bf16 scatter o=(h,d), m=(b,n) -> [B,H,N,DH].
// blockIdx.z selects (W,C) pair.
// ---------------------------------------------------------------------------
__global__ __launch_bounds__(256, 2) void gemm_bt(
    const u16* __restrict__ A,
    const u16* __restrict__ W0, const u16* __restrict__ W1, const u16* __restrict__ W2,
    void* __restrict__ C0, void* __restrict__ C1, void* __restrict__ C2,
    int mode)
{
    __shared__ __align__(16) char smem[32768];
    char* ldsA = smem;            // 16KB: 128 rows x 8 chunks x 16B
    char* ldsW = smem + 16384;

    const u16* W = (blockIdx.z == 0) ? W0 : (blockIdx.z == 1 ? W1 : W2);
    void*      C = (blockIdx.z == 0) ? C0 : (blockIdx.z == 1 ? C1 : C2);

    const int tid  = threadIdx.x;
    const int lane = tid & 63;
    const int w    = tid >> 6;
    const int quad = lane >> 4;
    const int l15  = lane & 15;
    const int m0   = blockIdx.y * 128;
    const int n0   = blockIdx.x * 128;
    const int wr   = (w >> 1) * 64;
    const int wc   = (w & 1) * 64;

    f32x4 acc[4][4];
    const f32x4 fz = {0.f, 0.f, 0.f, 0.f};
    #pragma unroll
    for (int i = 0; i < 4; i++)
        #pragma unroll
        for (int j = 0; j < 4; j++) acc[i][j] = fz;

    for (int k0 = 0; k0 < DMODEL; k0 += 64) {
        __syncthreads();
        #pragma unroll
        for (int i = 0; i < 4; i++) {
            int linear = tid + i * 256;          // 0..1023
            int row = linear >> 3;
            int sc  = linear & 7;
            int gc  = sc ^ (row & 7);
            load16_to_lds(A + (size_t)(m0 + row) * DMODEL + k0 + gc * 8, ldsA + linear * 16);
            load16_to_lds(W + (size_t)(n0 + row) * DMODEL + k0 + gc * 8, ldsW + linear * 16);
        }
        __syncthreads();
        #pragma unroll
        for (int ks = 0; ks < 2; ks++) {
            s16x8 af[4], bf[4];
            #pragma unroll
            for (int mi = 0; mi < 4; mi++) {
                int row = wr + mi * 16 + l15;
                int ch  = (ks * 4 + quad) ^ (row & 7);
                af[mi] = *(const s16x8*)(ldsA + row * 128 + ch * 16);
            }
            #pragma unroll
            for (int ni = 0; ni < 4; ni++) {
                int row = wc + ni * 16 + l15;
                int ch  = (ks * 4 + quad) ^ (row & 7);
                bf[ni] = *(const s16x8*)(ldsW + row * 128 + ch * 16);
            }
            #pragma unroll
            for (int mi = 0; mi < 4; mi++)
                #pragma unroll
                for (int ni = 0; ni < 4; ni++)
                    acc[mi][ni] = __builtin_amdgcn_mfma_f32_16x16x32_bf16(
                        af[mi], bf[ni], acc[mi][ni], 0, 0, 0);
        }
    }

    // epilogue: D layout col=lane&15, row=quad*4+reg
    #pragma unroll
    for (int mi = 0; mi < 4; mi++) {
        #pragma unroll
        for (int r = 0; r < 4; r++) {
            int m = m0 + wr + mi * 16 + quad * 4 + r;
            #pragma unroll
            for (int ni = 0; ni < 4; ni++) {
                int o = n0 + wc + ni * 16 + l15;
                if (mode == 0) {
                    ((float*)C)[(size_t)m * DMODEL + o] = acc[mi][ni][r];
                } else {
                    int b = m >> 11, n = m & (NSEQ - 1);
                    int h = o >> 6,  d = o & 63;
                    ((u16*)C)[(((size_t)(b * NH + h)) * NSEQ + n) * DH + d] = f2bf(acc[mi][ni][r]);
                }
            }
        }
    }
}

// ---------------------------------------------------------------------------
// Row squared-norms of Q and K (bf16 in, fp32 out). One thread per row.
// ---------------------------------------------------------------------------
__global__ void row_norms(const u16* __restrict__ Q, const u16* __restrict__ K,
                          float* __restrict__ qn, float* __restrict__ kn)
{
    int row = blockIdx.x * 256 + threadIdx.x;    // 0 .. BH*NSEQ-1
    const u16* q = Q + (size_t)row * DH;
    const u16* k = K + (size_t)row * DH;
    float sq = 0.f, sk = 0.f;
    #pragma unroll
    for (int c = 0; c < 8; c++) {
        s16x8 vq = *(const s16x8*)(q + c * 8);
        s16x8 vk = *(const s16x8*)(k + c * 8);
        #pragma unroll
        for (int j = 0; j < 8; j++) {
            union { uint32_t i; float f; } xq, xk;
            xq.i = ((uint32_t)(u16)vq[j]) << 16;
            xk.i = ((uint32_t)(u16)vk[j]) << 16;
            sq = fmaf(xq.f, xq.f, sq);
            sk = fmaf(xk.f, xk.f, sk);
        }
    }
    qn[row] = sq; kn[row] = sk;
}

// ---------------------------------------------------------------------------
// Transpose V[bh][n][d] -> Vt[bh][d][n], 64x64 LDS tiles.
// ---------------------------------------------------------------------------
__global__ void transpose_v(const u16* __restrict__ V, u16* __restrict__ Vt)
{
    __shared__ __align__(16) u16 tile[64][72];
    int bh = blockIdx.y;
    int n0 = blockIdx.x * 64;
    const u16* src = V + ((size_t)bh * NSEQ + n0) * DH;
    int tid = threadIdx.x;
    #pragma unroll
    for (int i = 0; i < 2; i++) {
        int c = tid + i * 256;        // 0..511
        int n = c >> 3, ch = c & 7;
        *(s16x8*)(&tile[n][ch * 8]) = *(const s16x8*)(src + (size_t)n * DH + ch * 8);
    }
    __syncthreads();
    #pragma unroll
    for (int i = 0; i < 2; i++) {
        int c = tid + i * 256;
        int d = c >> 3, nch = c & 7;
        s16x8 v;
        #pragma unroll
        for (int j = 0; j < 8; j++) v[j] = (short)tile[nch * 8 + j][d];
        *(s16x8*)(Vt + ((size_t)bh * DH + d) * NSEQ + n0 + nch * 8) = v;
    }
}

// ---------------------------------------------------------------------------
// Attention. grid (NSEQ/128, BH), 256 threads. Wave w owns 32 query rows.
// Scores bounded in [-~1.5, 0] => no online-max needed; accumulate
// num = sum P*V and den = sum P directly.  P = exp(-arccosh(z)) = z-sqrt(z^2-1).
// Row-sum of P via MFMA against a ones-fragment (same C-layout as O).
// LDS: Ks [128][64] swz8, Vts [64][128] swz16, Ps [128][128] swz16 = 64KB.
// ---------------------------------------------------------------------------
__global__ __launch_bounds__(256, 2) void attn_kernel(
    const u16* __restrict__ Q,     // [BH][NSEQ][DH]
    const u16* __restrict__ K,     // [BH][NSEQ][DH]
    const u16* __restrict__ Vt,    // [BH][DH][NSEQ]
    const float* __restrict__ qn,
    const float* __restrict__ kn,
    u16* __restrict__ Out)         // [B][NSEQ][DMODEL]
{
    __shared__ __align__(16) char smem[65536];
    char* ldsK = smem;             // 16KB
    char* ldsV = smem + 16384;     // 16KB
    char* ldsP = smem + 32768;     // 32KB

    const int tid  = threadIdx.x;
    const int lane = tid & 63;
    const int w    = tid >> 6;
    const int quad = lane >> 4;
    const int l15  = lane & 15;
    const int bh   = blockIdx.y;
    const int i0   = blockIdx.x * 128;
    const int b    = bh >> 4;
    const int h    = bh & 15;
    const int rowbase = i0 + w * 32;

    // Q fragments (A-operand), persistent in registers
    s16x8 qf[2][2];
    #pragma unroll
    for (int mi = 0; mi < 2; mi++)
        #pragma unroll
        for (int ks = 0; ks < 2; ks++)
            qf[mi][ks] = *(const s16x8*)(Q + ((size_t)bh * NSEQ + rowbase + mi * 16 + l15) * DH
                                         + ks * 32 + quad * 8);

    f32x4 qnv[2], rr[2];
    #pragma unroll
    for (int mi = 0; mi < 2; mi++) {
        qnv[mi] = *(const f32x4*)(qn + (size_t)bh * NSEQ + rowbase + mi * 16 + quad * 4);
        #pragma unroll
        for (int r = 0; r < 4; r++) rr[mi][r] = 1.0f / (1.0f - qnv[mi][r]);
    }

    const f32x4 fz = {0.f, 0.f, 0.f, 0.f};
    f32x4 oacc[2][4], lsum[2];
    #pragma unroll
    for (int mi = 0; mi < 2; mi++) {
        lsum[mi] = fz;
        #pragma unroll
        for (int ni = 0; ni < 4; ni++) oacc[mi][ni] = fz;
    }

    s16x8 ones;
    #pragma unroll
    for (int j = 0; j < 8; j++) ones[j] = (short)0x3F80;  // bf16 1.0

    for (int j0 = 0; j0 < NSEQ; j0 += 128) {
        __syncthreads();
        #pragma unroll
        for (int i = 0; i < 4; i++) {
            int linear = tid + i * 256;   // 0..1023
            {   // K tile: 128 rows x 8 chunks
                int row = linear >> 3, sc = linear & 7, gc = sc ^ (row & 7);
                load16_to_lds(K + ((size_t)bh * NSEQ + j0 + row) * DH + gc * 8,
                              ldsK + linear * 16);
            }
            {   // Vt tile: 64 rows x 16 chunks
                int d = linear >> 4, sc = linear & 15, gc = sc ^ (d & 15);
                load16_to_lds(Vt + ((size_t)bh * DH + d) * NSEQ + j0 + gc * 8,
                              ldsV + linear * 16);
            }
        }
        __syncthreads();

        // S = Q K^T  (per wave: 32 rows x 128 cols)
        f32x4 s[2][8];
        #pragma unroll
        for (int mi = 0; mi < 2; mi++)
            #pragma unroll
            for (int ci = 0; ci < 8; ci++) s[mi][ci] = fz;
        #pragma unroll
        for (int ks = 0; ks < 2; ks++) {
            s16x8 kf[8];
            #pragma unroll
            for (int ci = 0; ci < 8; ci++) {
                int row = ci * 16 + l15;
                int ch  = (ks * 4 + quad) ^ (row & 7);
                kf[ci] = *(const s16x8*)(ldsK + row * 128 + ch * 16);
            }
            #pragma unroll
            for (int mi = 0; mi < 2; mi++)
                #pragma unroll
                for (int ci = 0; ci < 8; ci++)
                    s[mi][ci] = __builtin_amdgcn_mfma_f32_16x16x32_bf16(
                        qf[mi][ks], kf[ci], s[mi][ci], 0, 0, 0);
        }

        // transform scores -> P (bf16) into swizzled LDS (own rows only)
        #pragma unroll
        for (int ci = 0; ci < 8; ci++) {
            float knv = kn[(size_t)bh * NSEQ + j0 + ci * 16 + l15];
            float rc  = 1.0f / (1.0f - knv);
            #pragma unroll
            for (int mi = 0; mi < 2; mi++) {
                int prow = w * 32 + mi * 16 + quad * 4;
                #pragma unroll
                for (int r = 0; r < 4; r++) {
                    float qk   = s[mi][ci][r];
                    float diff = qnv[mi][r] + knv - 2.0f * qk;
                    float z    = fmaf(2.0f * diff, rr[mi][r] * rc, 1.0f);
                    z = fmaxf(z, 1.0f);
                    float p = z - sqrtf(fmaf(z, z, -1.0f));   // exp(-arccosh(z))
                    int row = prow + r;
                    int col = ci * 16 + l15;
                    *(u16*)(ldsP + row * 256 + (((col >> 3) ^ (row & 15)) * 16)
                            + (col & 7) * 2) = f2bf(p);
                }
            }
        }

        // O += P V ; lsum += P * ones
        #pragma unroll
        for (int ks = 0; ks < 4; ks++) {
            s16x8 vf[4];
            #pragma unroll
            for (int ni = 0; ni < 4; ni++) {
                int d  = ni * 16 + l15;
                int ch = (ks * 4 + quad) ^ (d & 15);
                vf[ni] = *(const s16x8*)(ldsV + d * 256 + ch * 16);
            }
            s16x8 pf[2];
            #pragma unroll
            for (int mi = 0; mi < 2; mi++) {
                int row = w * 32 + mi * 16 + l15;
                int ch  = (ks * 4 + quad) ^ (row & 15);
                pf[mi] = *(const s16x8*)(ldsP + row * 256 + ch * 16);
            }
            #pragma unroll
            for (int mi = 0; mi < 2; mi++) {
                lsum[mi] = __builtin_amdgcn_mfma_f32_16x16x32_bf16(pf[mi], ones, lsum[mi], 0, 0, 0);
                #pragma unroll
                for (int ni = 0; ni < 4; ni++)
                    oacc[mi][ni] = __builtin_amdgcn_mfma_f32_16x16x32_bf16(
                        pf[mi], vf[ni], oacc[mi][ni], 0, 0, 0);
            }
        }
    }

    // epilogue: normalize and store to [B][N][H*64+d]
    #pragma unroll
    for (int mi = 0; mi < 2; mi++) {
        #pragma unroll
        for (int r = 0; r < 4; r++) {
            int n = rowbase + mi * 16 + quad * 4 + r;
            float rls = 1.0f / lsum[mi][r];
            #pragma unroll
            for (int ni = 0; ni < 4; ni++) {
                float o = oacc[mi][ni][r] * rls;
                Out[((size_t)b * NSEQ + n) * DMODEL + h * DH + ni * 16 + l15] = f2bf(o);
            }
        }
    }
}

// ---------------------------------------------------------------------------
extern "C" void kernel_launch(void* const* d_in, const int* in_sizes, int n_in,
                              void* d_out, int out_size, void* d_ws, size_t ws_size,
                              hipStream_t stream)
{
    const float* x  = (const float*)d_in[0];
    const float* wq = (const float*)d_in[1];
    const float* wk = (const float*)d_in[2];
    const float* wv = (const float*)d_in[3];
    const float* wo = (const float*)d_in[4];
    float* out = (float*)d_out;

    const size_t QSZ = (size_t)BH * NSEQ * DH;   // 4,194,304 elements
    const size_t WSZ = (size_t)DMODEL * DMODEL;  // 1,048,576 elements
    u16* xb   = (u16*)d_ws;           // 4M
    u16* wqb  = xb  + QSZ;            // 1M each
    u16* wkb  = wqb + WSZ;
    u16* wvb  = wkb + WSZ;
    u16* wob  = wvb + WSZ;
    u16* Qw   = wob + WSZ;
    u16* Kw   = Qw + QSZ;
    u16* Vw   = Kw + QSZ;
    u16* Vtw  = Vw + QSZ;
    u16* Attw = Vtw + QSZ;
    float* qnw = (float*)(Attw + QSZ);
    float* knw = qnw + (size_t)BH * NSEQ;

    // 0. fp32 -> bf16 conversions (x and the four weights)
    cvt_kernel<<<dim3(512, 1, 8), 256, 0, stream>>>(x, wq, wk, wv, wo,
                                                    xb, wqb, wkb, wvb, wob);
    // 1. Q/K/V projections (z selects weight), scatter to [B,H,N,DH]
    gemm_bt<<<dim3(8, 32, 3), 256, 0, stream>>>(xb, wqb, wkb, wvb, Qw, Kw, Vw, 1);
    // 2. row norms
    row_norms<<<dim3((BH * NSEQ) / 256), 256, 0, stream>>>(Qw, Kw, qnw, knw);
    // 3. V transpose per head
    transpose_v<<<dim3(NSEQ / 64, BH), 256, 0, stream>>>(Vw, Vtw);
    // 4. attention
    attn_kernel<<<dim3(NSEQ / 128, BH), 256, 0, stream>>>(Qw, Kw, Vtw, qnw, knw, Attw);
    // 5. output projection -> d_out (fp32)
    gemm_bt<<<dim3(8, 32, 1), 256, 0, stream>>>(Attw, wob, wob, wob, out, out, out, 0);
}

// Round 3
// 244.723 us; speedup vs baseline: 1.2309x; 1.2309x over previous
//
#include <hip/hip_runtime.h>
#include <hip/hip_bf16.h>
#include <stdint.h>

#define NSEQ   2048
#define DMODEL 1024
#define NH     16
#define DH     64
#define BATCH  2
#define BH     (BATCH*NH)           // 32
#define MROWS  (BATCH*NSEQ)         // 4096

typedef unsigned short u16;
typedef __attribute__((ext_vector_type(8))) short s16x8;
typedef __attribute__((ext_vector_type(4))) float f32x4;

__device__ __forceinline__ void load16_to_lds(const void* g, void* l) {
    __builtin_amdgcn_global_load_lds(
        (const __attribute__((address_space(1))) void*)g,
        (__attribute__((address_space(3))) void*)l,
        16, 0, 0);
}

__device__ __forceinline__ u16 f2bf(float f) {
    union { float f; uint32_t i; } x; x.f = f;
    uint32_t r = x.i + 0x7FFFu + ((x.i >> 16) & 1u);  // RNE
    return (u16)(r >> 16);
}

// pack two fp32 -> bf16 pair (lo in low16, hi in high16); round-half-down
__device__ __forceinline__ uint32_t pk2(float lo, float hi) {
    union { float f; uint32_t i; } a, b; a.f = lo; b.f = hi;
    return __builtin_amdgcn_perm(b.i + 0x7FFFu, a.i + 0x7FFFu, 0x07060302u);
}

// ---------------------------------------------------------------------------
// fp32 -> bf16 conversion. grid (512,1,8): z<4 -> quarter-slices of x (4M),
// z=4..7 -> wq/wk/wv/wo (1M each). 256 thr x 8 elem = 2048 per block.
// ---------------------------------------------------------------------------
__global__ void cvt_kernel(
    const float* __restrict__ x,
    const float* __restrict__ wq, const float* __restrict__ wk,
    const float* __restrict__ wv, const float* __restrict__ wo,
    u16* __restrict__ xb,
    u16* __restrict__ wqb, u16* __restrict__ wkb,
    u16* __restrict__ wvb, u16* __restrict__ wob)
{
    int z = blockIdx.z;
    const float* s = (z < 4) ? x  : (z == 4 ? wq  : z == 5 ? wk  : z == 6 ? wv  : wo);
    u16*         d = (z < 4) ? xb : (z == 4 ? wqb : z == 5 ? wkb : z == 6 ? wvb : wob);
    size_t off = (z < 4) ? ((size_t)z << 20) : 0;
    size_t i = off + (size_t)blockIdx.x * 2048 + (size_t)threadIdx.x * 8;
    float4 a = *(const float4*)(s + i);
    float4 b = *(const float4*)(s + i + 4);
    s16x8 v;
    v[0] = (short)f2bf(a.x); v[1] = (short)f2bf(a.y);
    v[2] = (short)f2bf(a.z); v[3] = (short)f2bf(a.w);
    v[4] = (short)f2bf(b.x); v[5] = (short)f2bf(b.y);
    v[6] = (short)f2bf(b.z); v[7] = (short)f2bf(b.w);
    *(s16x8*)(d + i) = v;
}

// ---------------------------------------------------------------------------
// GEMM: C = A @ W^T.  A:[M][1024] bf16 row-major, W:[1024][1024] bf16 row-major.
// 128x128 tile, BK=64, 256 threads (4 waves, each 64x64 = 4x4 MFMA tiles).
// XOR chunk swizzle: chunk c of row r stored at c ^ (r&7).
// mode 0: fp32 C[m][o].  mode 1: bf16 scatter -> [B,H,N,DH].
// ---------------------------------------------------------------------------
__global__ __launch_bounds__(256, 2) void gemm_bt(
    const u16* __restrict__ A,
    const u16* __restrict__ W0, const u16* __restrict__ W1, const u16* __restrict__ W2,
    void* __restrict__ C0, void* __restrict__ C1, void* __restrict__ C2,
    int mode)
{
    __shared__ __align__(16) char smem[32768];
    char* ldsA = smem;            // 16KB: 128 rows x 8 chunks x 16B
    char* ldsW = smem + 16384;

    const u16* W = (blockIdx.z == 0) ? W0 : (blockIdx.z == 1 ? W1 : W2);
    void*      C = (blockIdx.z == 0) ? C0 : (blockIdx.z == 1 ? C1 : C2);

    const int tid  = threadIdx.x;
    const int lane = tid & 63;
    const int w    = tid >> 6;
    const int quad = lane >> 4;
    const int l15  = lane & 15;
    const int m0   = blockIdx.y * 128;
    const int n0   = blockIdx.x * 128;
    const int wr   = (w >> 1) * 64;
    const int wc   = (w & 1) * 64;

    f32x4 acc[4][4];
    const f32x4 fz = {0.f, 0.f, 0.f, 0.f};
    #pragma unroll
    for (int i = 0; i < 4; i++)
        #pragma unroll
        for (int j = 0; j < 4; j++) acc[i][j] = fz;

    for (int k0 = 0; k0 < DMODEL; k0 += 64) {
        __syncthreads();
        #pragma unroll
        for (int i = 0; i < 4; i++) {
            int linear = tid + i * 256;          // 0..1023
            int row = linear >> 3;
            int sc  = linear & 7;
            int gc  = sc ^ (row & 7);
            load16_to_lds(A + (size_t)(m0 + row) * DMODEL + k0 + gc * 8, ldsA + linear * 16);
            load16_to_lds(W + (size_t)(n0 + row) * DMODEL + k0 + gc * 8, ldsW + linear * 16);
        }
        __syncthreads();
        #pragma unroll
        for (int ks = 0; ks < 2; ks++) {
            s16x8 af[4], bf[4];
            #pragma unroll
            for (int mi = 0; mi < 4; mi++) {
                int row = wr + mi * 16 + l15;
                int ch  = (ks * 4 + quad) ^ (row & 7);
                af[mi] = *(const s16x8*)(ldsA + row * 128 + ch * 16);
            }
            #pragma unroll
            for (int ni = 0; ni < 4; ni++) {
                int row = wc + ni * 16 + l15;
                int ch  = (ks * 4 + quad) ^ (row & 7);
                bf[ni] = *(const s16x8*)(ldsW + row * 128 + ch * 16);
            }
            #pragma unroll
            for (int mi = 0; mi < 4; mi++)
                #pragma unroll
                for (int ni = 0; ni < 4; ni++)
                    acc[mi][ni] = __builtin_amdgcn_mfma_f32_16x16x32_bf16(
                        af[mi], bf[ni], acc[mi][ni], 0, 0, 0);
        }
    }

    #pragma unroll
    for (int mi = 0; mi < 4; mi++) {
        #pragma unroll
        for (int r = 0; r < 4; r++) {
            int m = m0 + wr + mi * 16 + quad * 4 + r;
            #pragma unroll
            for (int ni = 0; ni < 4; ni++) {
                int o = n0 + wc + ni * 16 + l15;
                if (mode == 0) {
                    ((float*)C)[(size_t)m * DMODEL + o] = acc[mi][ni][r];
                } else {
                    int b = m >> 11, n = m & (NSEQ - 1);
                    int h = o >> 6,  d = o & 63;
                    ((u16*)C)[(((size_t)(b * NH + h)) * NSEQ + n) * DH + d] = f2bf(acc[mi][ni][r]);
                }
            }
        }
    }
}

// ---------------------------------------------------------------------------
// Row norms -> hyperbolic factor tables.
// qtab[row] = ( (1+|q|^2)/(1-|q|^2), 2/(1-|q|^2) ), same for ktab.
// z = Pr*Pc - (Rr*Rc)*qk  reproduces 1 + 2*diff/((1-qn)(1-kn)).
// ---------------------------------------------------------------------------
__global__ void make_tables(const u16* __restrict__ Q, const u16* __restrict__ K,
                            float2* __restrict__ qtab, float2* __restrict__ ktab)
{
    int row = blockIdx.x * 256 + threadIdx.x;    // 0 .. BH*NSEQ-1
    const u16* q = Q + (size_t)row * DH;
    const u16* k = K + (size_t)row * DH;
    float sq = 0.f, sk = 0.f;
    #pragma unroll
    for (int c = 0; c < 8; c++) {
        s16x8 vq = *(const s16x8*)(q + c * 8);
        s16x8 vk = *(const s16x8*)(k + c * 8);
        #pragma unroll
        for (int j = 0; j < 8; j++) {
            union { uint32_t i; float f; } xq, xk;
            xq.i = ((uint32_t)(u16)vq[j]) << 16;
            xk.i = ((uint32_t)(u16)vk[j]) << 16;
            sq = fmaf(xq.f, xq.f, sq);
            sk = fmaf(xk.f, xk.f, sk);
        }
    }
    float rq = 1.0f / (1.0f - sq);
    float rk = 1.0f / (1.0f - sk);
    qtab[row] = make_float2((1.0f + sq) * rq, 2.0f * rq);
    ktab[row] = make_float2((1.0f + sk) * rk, 2.0f * rk);
}

// ---------------------------------------------------------------------------
// Transpose V[bh][n][d] -> Vt[bh][d][n], 64x64 LDS tiles.
// ---------------------------------------------------------------------------
__global__ void transpose_v(const u16* __restrict__ V, u16* __restrict__ Vt)
{
    __shared__ __align__(16) u16 tile[64][72];
    int bh = blockIdx.y;
    int n0 = blockIdx.x * 64;
    const u16* src = V + ((size_t)bh * NSEQ + n0) * DH;
    int tid = threadIdx.x;
    #pragma unroll
    for (int i = 0; i < 2; i++) {
        int c = tid + i * 256;        // 0..511
        int n = c >> 3, ch = c & 7;
        *(s16x8*)(&tile[n][ch * 8]) = *(const s16x8*)(src + (size_t)n * DH + ch * 8);
    }
    __syncthreads();
    #pragma unroll
    for (int i = 0; i < 2; i++) {
        int c = tid + i * 256;
        int d = c >> 3, nch = c & 7;
        s16x8 v;
        #pragma unroll
        for (int j = 0; j < 8; j++) v[j] = (short)tile[nch * 8 + j][d];
        *(s16x8*)(Vt + ((size_t)bh * DH + d) * NSEQ + n0 + nch * 8) = v;
    }
}

// ---------------------------------------------------------------------------
// Attention, transposed-score form.  grid (NSEQ/64, BH), 256 threads.
// Wave w owns q rows [i0+w*16, +16): S' = K Q^T (C-layout: col=q, row=j),
// transform in regs, B-fragment for O^T = V^T P^T built via ds_bpermute
// (no P LDS round-trip).  lsum via ones-MFMA.  LDS 32KB (K tile + Vt tile).
// ---------------------------------------------------------------------------
__global__ __launch_bounds__(256, 3) void attn_kernel(
    const u16* __restrict__ Q,      // [BH][NSEQ][DH]
    const u16* __restrict__ K,      // [BH][NSEQ][DH]
    const u16* __restrict__ Vt,     // [BH][DH][NSEQ]
    const float2* __restrict__ qtab,
    const float2* __restrict__ ktab,
    u16* __restrict__ Out)          // [B][NSEQ][DMODEL]
{
    __shared__ __align__(16) char smem[32768];
    char* ldsK = smem;              // 16KB: 128 j-rows x 8 chunks, swz8
    char* ldsV = smem + 16384;      // 16KB: 64 d-rows x 16 chunks, swz16

    const int tid  = threadIdx.x;
    const int lane = tid & 63;
    const int w    = tid >> 6;
    const int quad = lane >> 4;
    const int l15  = lane & 15;
    const int bh   = blockIdx.y;
    const int i0   = blockIdx.x * 64;
    const int b    = bh >> 4;
    const int h    = bh & 15;
    const int qrow = i0 + w * 16 + l15;

    // Q fragment doubles as the MFMA B-operand (same register layout)
    s16x8 qf[2];
    #pragma unroll
    for (int ks = 0; ks < 2; ks++)
        qf[ks] = *(const s16x8*)(Q + ((size_t)bh * NSEQ + qrow) * DH + ks * 32 + quad * 8);

    const float2 qt = qtab[(size_t)bh * NSEQ + qrow];
    const float Pr = qt.x, Rr = qt.y;

    // bpermute source-lane byte indices: q' = 2*(quad&1) (+1 for idx2)
    const int idx0 = ((quad & 1) * 32 + l15) * 4;
    const int idx2 = idx0 + 64;
    const bool selhi = quad >= 2;

    const f32x4 fz = {0.f, 0.f, 0.f, 0.f};
    f32x4 oacc[4];                  // O^T: 4 d-tiles x 1 q-tile (col=q, row=d)
    f32x4 lsum = fz;
    #pragma unroll
    for (int ni = 0; ni < 4; ni++) oacc[ni] = fz;

    s16x8 ones;
    #pragma unroll
    for (int j = 0; j < 8; j++) ones[j] = (short)0x3F80;  // bf16 1.0

    for (int j0 = 0; j0 < NSEQ; j0 += 128) {
        __syncthreads();
        #pragma unroll
        for (int i = 0; i < 4; i++) {
            int linear = tid + i * 256;   // 0..1023
            {   // K tile: 128 rows x 8 chunks
                int row = linear >> 3, sc = linear & 7, gc = sc ^ (row & 7);
                load16_to_lds(K + ((size_t)bh * NSEQ + j0 + row) * DH + gc * 8,
                              ldsK + linear * 16);
            }
            {   // Vt tile: 64 rows x 16 chunks
                int d = linear >> 4, sc = linear & 15, gc = sc ^ (d & 15);
                load16_to_lds(Vt + ((size_t)bh * DH + d) * NSEQ + j0 + gc * 8,
                              ldsV + linear * 16);
            }
        }
        __syncthreads();

        #pragma unroll
        for (int cb = 0; cb < 4; cb++) {          // 32 j per chunk
            // S' = K Q^T for two 16-j tiles
            f32x4 s2[2] = {fz, fz};
            #pragma unroll
            for (int t = 0; t < 2; t++) {
                int row = (cb * 2 + t) * 16 + l15;
                #pragma unroll
                for (int ks = 0; ks < 2; ks++) {
                    s16x8 kf = *(const s16x8*)(ldsK + row * 128
                                 + (((ks * 4 + quad) ^ (row & 7)) * 16));
                    s2[t] = __builtin_amdgcn_mfma_f32_16x16x32_bf16(kf, qf[ks], s2[t], 0, 0, 0);
                }
            }
            // transform + pack (bf16 pairs in C-layout)
            uint32_t d0[2], d1[2];
            #pragma unroll
            for (int t = 0; t < 2; t++) {
                const f32x4* kt = (const f32x4*)(ktab + (size_t)bh * NSEQ + j0
                                                 + (cb * 2 + t) * 16 + quad * 4);
                f32x4 c01 = kt[0], c23 = kt[1];
                float p0, p1, p2, p3;
                {
                    float z = fmaf(-s2[t][0] * c01.y, Rr, Pr * c01.x);
                    z = fmaxf(z, 1.0f);
                    p0 = z - __builtin_amdgcn_sqrtf(fmaf(z, z, -1.0f));
                }
                {
                    float z = fmaf(-s2[t][1] * c01.w, Rr, Pr * c01.z);
                    z = fmaxf(z, 1.0f);
                    p1 = z - __builtin_amdgcn_sqrtf(fmaf(z, z, -1.0f));
                }
                {
                    float z = fmaf(-s2[t][2] * c23.y, Rr, Pr * c23.x);
                    z = fmaxf(z, 1.0f);
                    p2 = z - __builtin_amdgcn_sqrtf(fmaf(z, z, -1.0f));
                }
                {
                    float z = fmaf(-s2[t][3] * c23.y * 0.0f + -s2[t][3] * c23.w, Rr, Pr * c23.z);
                    z = fmaxf(z, 1.0f);
                    p3 = z - __builtin_amdgcn_sqrtf(fmaf(z, z, -1.0f));
                }
                d0[t] = pk2(p0, p1);
                d1[t] = pk2(p2, p3);
            }
            // build P' B-fragment via cross-lane pulls
            int a0 = __builtin_amdgcn_ds_bpermute(idx0, (int)d0[0]);
            int b0 = __builtin_amdgcn_ds_bpermute(idx0, (int)d0[1]);
            int a1 = __builtin_amdgcn_ds_bpermute(idx0, (int)d1[0]);
            int b1 = __builtin_amdgcn_ds_bpermute(idx0, (int)d1[1]);
            int a2 = __builtin_amdgcn_ds_bpermute(idx2, (int)d0[0]);
            int b2 = __builtin_amdgcn_ds_bpermute(idx2, (int)d0[1]);
            int a3 = __builtin_amdgcn_ds_bpermute(idx2, (int)d1[0]);
            int b3 = __builtin_amdgcn_ds_bpermute(idx2, (int)d1[1]);
            union { int i[4]; s16x8 v; } pu;
            pu.i[0] = selhi ? b0 : a0;
            pu.i[1] = selhi ? b1 : a1;
            pu.i[2] = selhi ? b2 : a2;
            pu.i[3] = selhi ? b3 : a3;
            s16x8 pf = pu.v;

            // O^T += Vt-tile * P' ; lsum += ones * P'
            #pragma unroll
            for (int ni = 0; ni < 4; ni++) {
                int d = ni * 16 + l15;
                s16x8 vf = *(const s16x8*)(ldsV + d * 256
                             + (((cb * 4 + quad) ^ (d & 15)) * 16));
                oacc[ni] = __builtin_amdgcn_mfma_f32_16x16x32_bf16(vf, pf, oacc[ni], 0, 0, 0);
            }
            lsum = __builtin_amdgcn_mfma_f32_16x16x32_bf16(ones, pf, lsum, 0, 0, 0);
        }
    }

    // epilogue: O^T C-layout col=q(=l15), row=d; all 4 lsum entries equal
    float rls = 1.0f / lsum[0];
    size_t obase = ((size_t)b * NSEQ + qrow) * DMODEL + h * DH + quad * 4;
    #pragma unroll
    for (int ni = 0; ni < 4; ni++) {
        uint2 st;
        st.x = pk2(oacc[ni][0] * rls, oacc[ni][1] * rls);
        st.y = pk2(oacc[ni][2] * rls, oacc[ni][3] * rls);
        *(uint2*)(Out + obase + ni * 16) = st;
    }
}

// ---------------------------------------------------------------------------
extern "C" void kernel_launch(void* const* d_in, const int* in_sizes, int n_in,
                              void* d_out, int out_size, void* d_ws, size_t ws_size,
                              hipStream_t stream)
{
    const float* x  = (const float*)d_in[0];
    const float* wq = (const float*)d_in[1];
    const float* wk = (const float*)d_in[2];
    const float* wv = (const float*)d_in[3];
    const float* wo = (const float*)d_in[4];
    float* out = (float*)d_out;

    const size_t QSZ = (size_t)BH * NSEQ * DH;   // 4,194,304 elements
    const size_t WSZ = (size_t)DMODEL * DMODEL;  // 1,048,576 elements
    u16* xb   = (u16*)d_ws;           // 4M elem; reused as Attw after attn
    u16* wqb  = xb  + QSZ;
    u16* wkb  = wqb + WSZ;
    u16* wvb  = wkb + WSZ;
    u16* wob  = wvb + WSZ;
    u16* Qw   = wob + WSZ;
    u16* Kw   = Qw + QSZ;
    u16* Vw   = Kw + QSZ;
    u16* Vtw  = Vw + QSZ;
    float2* qtab = (float2*)(Vtw + QSZ);
    float2* ktab = qtab + (size_t)BH * NSEQ;
    u16* Attw = xb;                   // overlay: x bf16 no longer needed post-QKV

    // 0. fp32 -> bf16 conversions
    cvt_kernel<<<dim3(512, 1, 8), 256, 0, stream>>>(x, wq, wk, wv, wo,
                                                    xb, wqb, wkb, wvb, wob);
    // 1. Q/K/V projections, scatter to [B,H,N,DH]
    gemm_bt<<<dim3(8, 32, 3), 256, 0, stream>>>(xb, wqb, wkb, wvb, Qw, Kw, Vw, 1);
    // 2. hyperbolic factor tables
    make_tables<<<dim3((BH * NSEQ) / 256), 256, 0, stream>>>(Qw, Kw, qtab, ktab);
    // 3. V transpose per head
    transpose_v<<<dim3(NSEQ / 64, BH), 256, 0, stream>>>(Vw, Vtw);
    // 4. attention (transposed-score form)
    attn_kernel<<<dim3(NSEQ / 64, BH), 256, 0, stream>>>(Qw, Kw, Vtw, qtab, ktab, Attw);
    // 5. output projection -> d_out (fp32)
    gemm_bt<<<dim3(8, 32, 1), 256, 0, stream>>>(Attw, wob, wob, wob, out, out, out, 0);
}